// Round 8
// baseline (73.198 us; speedup 1.0000x reference)
//
#include <hip/hip_runtime.h>
#include <hip/hip_bf16.h>

#define BATCH   32
#define IN_DIM  2048
#define OUT_DIM 2048
#define ZDIM    64
#define NNZ     209715
#define CAP     160                       // max nnz per col ~138 (mean 102.4); 160 = +5.7 sigma
#define TILES   ((NNZ + 15) / 16)         // 13108
#define CBLOCKS ((TILES + 3) / 4)         // 3277 blocks, 1 wave = 1 tile (best occupancy, r6)
#define NBLK    ((NNZ + 1023) / 1024)     // 205 rank blocks

typedef __attribute__((ext_vector_type(8))) short bf16x8;
typedef __attribute__((ext_vector_type(4))) float f32x4;

// ---------------- workspace layout (byte offsets) ----------------
// xT       : float[2048*32]        @ 0          (x transposed)
// cnt      : int[2048]             @ 262144     (per-column counts)
// blockHist: int[NBLK][2048]       @ 270336     (then per-block bases after colscan)
// rowOf    : int[NNZ]              @ 1949696    (E row for each k)
// E        : bf16[2048*CAP*32]     @ 2788608
#define OFF_XT   0
#define OFF_CNT  262144
#define OFF_BH   270336
#define OFF_ROW  1949696
#define OFF_E    2788608
#define B_WS_NEEDED (OFF_E + (size_t)OUT_DIM * CAP * BATCH * 2)   // ~23.8 MB

__device__ __forceinline__ short f2bf(float f) {      // RNE f32 -> bf16
    unsigned u = __float_as_uint(f);
    u += 0x7fffu + ((u >> 16) & 1u);
    return (short)(u >> 16);
}

// ---- prep: transpose x -> xT[i*32+b]; 256 blocks x 256 ----
__global__ __launch_bounds__(256) void prep_x(
    const float* __restrict__ x, float* __restrict__ xT)
{
    const int idx = blockIdx.x * 256 + threadIdx.x;   // exactly 65536
    const int b = idx >> 11;
    const int i = idx & 2047;
    xT[i * BATCH + b] = x[idx];
}

// ---- rank stage A: per-block LDS histogram of out_idx ----
__global__ __launch_bounds__(1024) void hist_blk(
    const int* __restrict__ out_idx, int* __restrict__ blockHist)
{
    __shared__ int lh[OUT_DIM];
    const int t = threadIdx.x, blk = blockIdx.x;
    lh[t] = 0; lh[t + 1024] = 0;
    __syncthreads();
    const int k = blk * 1024 + t;
    if (k < NNZ) atomicAdd(&lh[out_idx[k]], 1);       // LDS atomic: ~free
    __syncthreads();
    blockHist[blk * OUT_DIM + t]        = lh[t];          // coalesced 8KB row
    blockHist[blk * OUT_DIM + t + 1024] = lh[t + 1024];
}

// ---- rank stage B: per-column exclusive scan over blocks; emit cnt ----
__global__ __launch_bounds__(256) void colscan(
    int* __restrict__ blockHist, int* __restrict__ cnt)
{
    const int o = blockIdx.x * 256 + threadIdx.x;     // 8 blocks -> 2048 columns
    int run = 0;
    #pragma unroll 4
    for (int blk = 0; blk < NBLK; ++blk) {
        const int v = blockHist[blk * OUT_DIM + o];   // coalesced across threads
        blockHist[blk * OUT_DIM + o] = run;           // in-place: base for slot_blk
        run += v;
    }
    cnt[o] = run;
}

// ---- rank stage C: local LDS rank + block base -> rowOf[k] ----
__global__ __launch_bounds__(1024) void slot_blk(
    const int* __restrict__ out_idx, const int* __restrict__ blockHist,
    int* __restrict__ rowOf)
{
    __shared__ int lh[OUT_DIM];
    const int t = threadIdx.x, blk = blockIdx.x;
    lh[t] = 0; lh[t + 1024] = 0;
    __syncthreads();
    const int k = blk * 1024 + t;
    if (k < NNZ) {
        const int oi  = out_idx[k];
        const int r   = atomicAdd(&lh[oi], 1);                 // rank within block
        const int pos = blockHist[blk * OUT_DIM + oi] + r;     // + blocks before
        rowOf[k] = (pos < CAP) ? oi * CAP + pos : -1;
    }
}

// ---- main compute: one wave per 16-k tile; NO atomics, plain W loads ----
__global__ __launch_bounds__(256) void compute_mfma(
    const float* __restrict__ z, const float* __restrict__ W,
    const float* __restrict__ bn, const int* __restrict__ in_idx,
    const int* __restrict__ rowOf, const float* __restrict__ xT,
    short* __restrict__ E)
{
    const int lane = threadIdx.x & 63;
    const int m    = lane & 15;            // A-row (k in tile) / B,C col (b)
    const int hi   = lane >> 4;            // k-slice group for inputs
    const int t    = blockIdx.x * 4 + (threadIdx.x >> 6);   // tile id == wave id
    if (t >= TILES) return;
    const int k0 = t * 16;

    // per-k metadata (lanes 0..15): plain coalesced 64B loads, no atomic chain.
    int rowL = -1, iiL = 0; float bnL = 0.f;
    if (lane < 16) {
        const int kk = k0 + lane;
        if (kk < NNZ) {
            rowL = rowOf[kk];
            iiL  = in_idx[kk];
            bnL  = bn[kk];
        }
    }

    // A-fragment: A[m, j] = W[j][k0+m]; 16 coalesced dword loads.
    // Plain (cached) loads: W + E + xT (~76 MB) fit in the 256MB L3, so W
    // stays L3-resident across graph replays.
    const int kA = (k0 + m < NNZ) ? (k0 + m) : (NNZ - 1);
    const float* wp = W + (size_t)(hi * 8) * NNZ + kA;
    float wv[16];
    #pragma unroll
    for (int e = 0; e < 8; ++e) wv[e]     = wp[(size_t)e * NNZ];
    #pragma unroll
    for (int e = 0; e < 8; ++e) wv[8 + e] = wp[(size_t)(32 + e) * NNZ];

    // B-fragments: B[j, b] = z[b][j]; b = bt*16 + m, j = jt*32 + hi*8 + e.
    bf16x8 zf[2][2];
    #pragma unroll
    for (int bt = 0; bt < 2; ++bt)
        #pragma unroll
        for (int jt = 0; jt < 2; ++jt) {
            const float* zp = z + (bt * 16 + m) * ZDIM + jt * 32 + hi * 8;
            const float4 a = *reinterpret_cast<const float4*>(zp);
            const float4 c = *reinterpret_cast<const float4*>(zp + 4);
            union { bf16x8 v; short s[8]; } u;
            u.s[0] = f2bf(a.x); u.s[1] = f2bf(a.y); u.s[2] = f2bf(a.z); u.s[3] = f2bf(a.w);
            u.s[4] = f2bf(c.x); u.s[5] = f2bf(c.y); u.s[6] = f2bf(c.z); u.s[7] = f2bf(c.w);
            zf[bt][jt] = u.v;
        }

    union { bf16x8 v; short s[8]; } a0, a1;
    #pragma unroll
    for (int e = 0; e < 8; ++e) { a0.s[e] = f2bf(wv[e]); a1.s[e] = f2bf(wv[8 + e]); }

    f32x4 acc0 = {0.f, 0.f, 0.f, 0.f};
    f32x4 acc1 = {0.f, 0.f, 0.f, 0.f};
    acc0 = __builtin_amdgcn_mfma_f32_16x16x32_bf16(a0.v, zf[0][0], acc0, 0, 0, 0);
    acc0 = __builtin_amdgcn_mfma_f32_16x16x32_bf16(a1.v, zf[0][1], acc0, 0, 0, 0);
    acc1 = __builtin_amdgcn_mfma_f32_16x16x32_bf16(a0.v, zf[1][0], acc1, 0, 0, 0);
    acc1 = __builtin_amdgcn_mfma_f32_16x16x32_bf16(a1.v, zf[1][1], acc1, 0, 0, 0);

    // epilogue: lane holds C rows k = k0 + hi*4 + r, col b = bt*16 + m
    #pragma unroll
    for (int r = 0; r < 4; ++r) {
        const int src  = hi * 4 + r;
        const int row  = __shfl(rowL, src);
        const int ii   = __shfl(iiL, src);
        const float bb = __shfl(bnL, src);
        if (row >= 0) {
            const float x0 = xT[ii * BATCH + m];        // 64B per 16-lane group
            const float x1 = xT[ii * BATCH + 16 + m];
            short* Ep = E + (size_t)row * BATCH;
            Ep[m]      = f2bf((acc0[r] + bb) * x0);     // 32B coalesced per row-half
            Ep[16 + m] = f2bf((acc1[r] + bb) * x1);
        }
    }
}

// ---- segmented reduce: 2 cols/block, 2 waves/col, LDS combine, NO atomics ----
__global__ __launch_bounds__(256) void reduce_bf16(
    const short* __restrict__ E, const int* __restrict__ cnt,
    float* __restrict__ out)
{
    __shared__ float partial[2][BATCH];
    const int wave = threadIdx.x >> 6;          // 0..3
    const int lane = threadIdx.x & 63;
    const int cs   = wave >> 1;                 // column slot in block (0/1)
    const int part = wave & 1;                  // row-half
    const int o    = blockIdx.x * 2 + cs;       // 1024 blocks -> 2048 columns
    const int r  = lane >> 2;                   // 0..15 row-in-group
    const int bg = lane & 3;                    // b-octet
    const int s = o * CAP;
    int c = cnt[o]; if (c > CAP) c = CAP;
    const int e = s + c;

    float acc[8];
    #pragma unroll
    for (int q = 0; q < 8; ++q) acc[q] = 0.f;

    for (int p = s + part * 16 + r; p < e; p += 32) {
        const uint4 v = *reinterpret_cast<const uint4*>(E + (size_t)p * BATCH + bg * 8);
        const unsigned u[4] = {v.x, v.y, v.z, v.w};
        #pragma unroll
        for (int q = 0; q < 4; ++q) {
            acc[2 * q]     += __uint_as_float((u[q] & 0xFFFFu) << 16);
            acc[2 * q + 1] += __uint_as_float(u[q] & 0xFFFF0000u);
        }
    }

    #pragma unroll
    for (int d = 4; d < 64; d <<= 1)
        #pragma unroll
        for (int q = 0; q < 8; ++q)
            acc[q] += __shfl_xor(acc[q], d);

    if (part == 1 && lane < 4) {
        #pragma unroll
        for (int q = 0; q < 8; ++q) partial[cs][bg * 8 + q] = acc[q];
    }
    __syncthreads();
    if (part == 0 && lane < 4) {
        #pragma unroll
        for (int q = 0; q < 8; ++q)
            out[(bg * 8 + q) * OUT_DIM + o] = acc[q] + partial[cs][bg * 8 + q];
    }
}

// ---- last-resort fallback (tiny ws): round-1 atomic scatter ----
__global__ __launch_bounds__(256) void hyper_scatter_kernel(
    const float* __restrict__ x, const float* __restrict__ z,
    const float* __restrict__ W, const float* __restrict__ bn,
    const int* __restrict__ in_idx, const int* __restrict__ out_idx,
    float* __restrict__ out)
{
    __shared__ float zs[BATCH * ZDIM];
    const int tid = threadIdx.x;
    {
        const float4* zg  = reinterpret_cast<const float4*>(z);
        float4*       zsv = reinterpret_cast<float4*>(zs);
        zsv[tid]       = zg[tid];
        zsv[tid + 256] = zg[tid + 256];
    }
    __syncthreads();
    const int k = blockIdx.x * 256 + tid;
    if (k >= NNZ) return;
    float w[ZDIM];
    #pragma unroll
    for (int j = 0; j < ZDIM; ++j) w[j] = W[(size_t)j * NNZ + k];
    const float bk = bn[k];
    const int ii = in_idx[k], oi = out_idx[k];
    const float4* zv = reinterpret_cast<const float4*>(zs);
    #pragma unroll
    for (int b = 0; b < BATCH; ++b) {
        float e = bk;
        #pragma unroll
        for (int j4 = 0; j4 < ZDIM / 4; ++j4) {
            const float4 zz = zv[b * (ZDIM / 4) + j4];
            e = fmaf(zz.x, w[j4 * 4 + 0], e);
            e = fmaf(zz.y, w[j4 * 4 + 1], e);
            e = fmaf(zz.z, w[j4 * 4 + 2], e);
            e = fmaf(zz.w, w[j4 * 4 + 3], e);
        }
        atomicAdd(&out[b * OUT_DIM + oi], e * x[b * IN_DIM + ii]);
    }
}

extern "C" void kernel_launch(void* const* d_in, const int* in_sizes, int n_in,
                              void* d_out, int out_size, void* d_ws, size_t ws_size,
                              hipStream_t stream) {
    const float* x       = (const float*)d_in[0];
    const float* z       = (const float*)d_in[1];
    const float* W       = (const float*)d_in[2];
    const float* bn      = (const float*)d_in[3];
    const int*   in_idx  = (const int*)d_in[4];
    const int*   out_idx = (const int*)d_in[5];
    float*       out     = (float*)d_out;
    char*        ws      = (char*)d_ws;

    if (ws_size >= B_WS_NEEDED) {
        float* xT    = (float*)(ws + OFF_XT);
        int*   cnt   = (int*)(ws + OFF_CNT);
        int*   bh    = (int*)(ws + OFF_BH);
        int*   rowOf = (int*)(ws + OFF_ROW);
        short* E     = (short*)(ws + OFF_E);

        prep_x   <<<(BATCH * IN_DIM) / 256, 256, 0, stream>>>(x, xT);
        hist_blk <<<NBLK, 1024, 0, stream>>>(out_idx, bh);
        colscan  <<<OUT_DIM / 256, 256, 0, stream>>>(bh, cnt);
        slot_blk <<<NBLK, 1024, 0, stream>>>(out_idx, bh, rowOf);
        compute_mfma<<<CBLOCKS, 256, 0, stream>>>(z, W, bn, in_idx, rowOf, xT, E);
        reduce_bf16 <<<OUT_DIM / 2, 256, 0, stream>>>(E, cnt, out);
    } else {
        hipMemsetAsync(out, 0, (size_t)BATCH * OUT_DIM * sizeof(float), stream);
        const int grid = (NNZ + 255) / 256;
        hyper_scatter_kernel<<<grid, 256, 0, stream>>>(x, z, W, bn, in_idx, out_idx, out);
    }
}

// Round 9
// 46.317 us; speedup vs baseline: 1.5804x; 1.5804x over previous
//
#include <hip/hip_runtime.h>
#include <hip/hip_bf16.h>

#define BATCH   32
#define IN_DIM  2048
#define OUT_DIM 2048
#define ZDIM    64
#define NNZ     209715
#define CAP     160                       // max nnz per col ~138 (mean 102.4); 160 = +5.7 sigma
#define TILES   ((NNZ + 15) / 16)         // 13108
#define CBLOCKS ((TILES + 3) / 4)         // 3277 blocks, 1 wave = 1 tile
#define NBLK    ((NNZ + 1023) / 1024)     // 205 rank blocks

typedef __attribute__((ext_vector_type(8))) short bf16x8;
typedef __attribute__((ext_vector_type(4))) float f32x4;

// ---------------- workspace layout (byte offsets) ----------------
// xT   : float[2048*32]        @ 0           (x transposed)
// zbf  : bf16[32*64]           @ 262144      (z pre-converted to bf16, [b][j])
// cnt  : int[2048]             @ 270336      (per-column counts)
// bh   : int[2048][256]        @ 278528      (TRANSPOSED block hists / bases; 2MB)
// rowOf: int[NNZ]              @ 2375680     (E row for each k)
// E    : bf16[2048*CAP*32]     @ 3214592
#define OFF_XT   0
#define OFF_ZBF  262144
#define OFF_CNT  270336
#define OFF_BH   278528
#define OFF_ROW  2375680
#define OFF_E    3214592
#define B_WS_NEEDED (OFF_E + (size_t)OUT_DIM * CAP * BATCH * 2)   // ~24.2 MB

__device__ __forceinline__ short f2bf(float f) {      // RNE f32 -> bf16
    unsigned u = __float_as_uint(f);
    u += 0x7fffu + ((u >> 16) & 1u);
    return (short)(u >> 16);
}

// ---- prep: transpose x -> xT[i*32+b]; convert z -> zbf; 256 blocks x 256 ----
__global__ __launch_bounds__(256) void prep_x(
    const float* __restrict__ x, const float* __restrict__ z,
    float* __restrict__ xT, short* __restrict__ zbf)
{
    const int idx = blockIdx.x * 256 + threadIdx.x;   // exactly 65536
    const int b = idx >> 11;
    const int i = idx & 2047;
    xT[i * BATCH + b] = x[idx];
    if (idx < BATCH * ZDIM) zbf[idx] = f2bf(z[idx]);  // [b][j] bf16 copy
}

// ---- rank stage A: per-block LDS histogram -> bh[o][blk] (transposed) ----
__global__ __launch_bounds__(1024) void hist_blk(
    const int* __restrict__ out_idx, int* __restrict__ bh)
{
    __shared__ int lh[OUT_DIM];
    const int t = threadIdx.x, blk = blockIdx.x;
    lh[t] = 0; lh[t + 1024] = 0;
    __syncthreads();
    const int k = blk * 1024 + t;
    if (k < NNZ) atomicAdd(&lh[out_idx[k]], 1);       // LDS atomic: ~free
    __syncthreads();
    bh[t * 256 + blk]          = lh[t];               // scattered 4B (L2)
    bh[(t + 1024) * 256 + blk] = lh[t + 1024];
}

// ---- rank stage B: wave-per-column shuffle scan; 512 blocks x 4 waves ----
__global__ __launch_bounds__(256) void colscan(
    int* __restrict__ bh, int* __restrict__ cnt)
{
    const int o    = blockIdx.x * 4 + (threadIdx.x >> 6);  // 2048 columns
    const int lane = threadIdx.x & 63;
    const int i0   = lane * 4;
    int4 v = *reinterpret_cast<int4*>(bh + o * 256 + i0);  // coalesced 1KB/wave
    const int a = (i0 + 0 < NBLK) ? v.x : 0;               // mask poison tail
    const int b = (i0 + 1 < NBLK) ? v.y : 0;
    const int c = (i0 + 2 < NBLK) ? v.z : 0;
    const int d = (i0 + 3 < NBLK) ? v.w : 0;
    const int s1 = a + b, s2 = s1 + c, tot = s2 + d;
    int inc = tot;
    #pragma unroll
    for (int t = 1; t < 64; t <<= 1) {
        const int n = __shfl_up(inc, t);
        if (lane >= t) inc += n;
    }
    const int exc = inc - tot;
    int4 w; w.x = exc; w.y = exc + a; w.z = exc + s1; w.w = exc + s2;
    *reinterpret_cast<int4*>(bh + o * 256 + i0) = w;
    if (lane == 63) cnt[o] = inc;
}

// ---- rank stage C: local LDS rank + block base -> rowOf[k] ----
__global__ __launch_bounds__(1024) void slot_blk(
    const int* __restrict__ out_idx, const int* __restrict__ bh,
    int* __restrict__ rowOf)
{
    __shared__ int lh[OUT_DIM];
    const int t = threadIdx.x, blk = blockIdx.x;
    lh[t] = 0; lh[t + 1024] = 0;
    __syncthreads();
    const int k = blk * 1024 + t;
    if (k < NNZ) {
        const int oi  = out_idx[k];
        const int r   = atomicAdd(&lh[oi], 1);            // rank within block
        const int pos = bh[oi * 256 + blk] + r;           // + blocks before
        rowOf[k] = (pos < CAP) ? oi * CAP + pos : -1;
    }
}

// ---- main compute: one wave per 16-k tile; min-waves=4 buys VGPRs for ILP ----
// All 16 W loads + 4 z-fragment loads issue back-to-back (one waitcnt), no
// register-pressure chunking (the r5-r8 serialization bug at VGPR<=64).
__global__ __launch_bounds__(256, 4) void compute_mfma(
    const short* __restrict__ zbf, const float* __restrict__ W,
    const float* __restrict__ bn, const int* __restrict__ in_idx,
    const int* __restrict__ rowOf, const float* __restrict__ xT,
    short* __restrict__ E)
{
    const int lane = threadIdx.x & 63;
    const int m    = lane & 15;            // A-row (k in tile) / B,C col (b)
    const int hi   = lane >> 4;            // k-slice group for inputs
    const int t    = blockIdx.x * 4 + (threadIdx.x >> 6);   // tile id == wave id
    if (t >= TILES) return;
    const int k0 = t * 16;

    // B-fragments: direct 16B loads of pre-converted bf16 z (no cvt, 4 loads).
    // B[j, b] = z[b][j]; b = bt*16 + m, j = jt*32 + hi*8 + e.
    bf16x8 zf[2][2];
    #pragma unroll
    for (int bt = 0; bt < 2; ++bt)
        #pragma unroll
        for (int jt = 0; jt < 2; ++jt)
            zf[bt][jt] = *reinterpret_cast<const bf16x8*>(
                zbf + (bt * 16 + m) * ZDIM + jt * 32 + hi * 8);

    // A-fragment: A[m, j] = W[j][k0+m]; 16 coalesced dword loads, all in flight.
    const int kA = (k0 + m < NNZ) ? (k0 + m) : (NNZ - 1);
    const float* wp = W + (size_t)(hi * 8) * NNZ + kA;
    float wv[16];
    #pragma unroll
    for (int e = 0; e < 8; ++e) wv[e]     = wp[(size_t)e * NNZ];
    #pragma unroll
    for (int e = 0; e < 8; ++e) wv[8 + e] = wp[(size_t)(32 + e) * NNZ];

    // per-k metadata (lanes 0..15): plain coalesced 64B loads.
    int rowL = -1, iiL = 0; float bnL = 0.f;
    if (lane < 16) {
        const int kk = k0 + lane;
        if (kk < NNZ) {
            rowL = rowOf[kk];
            iiL  = in_idx[kk];
            bnL  = bn[kk];
        }
    }

    union { bf16x8 v; short s[8]; } a0, a1;
    #pragma unroll
    for (int e = 0; e < 8; ++e) { a0.s[e] = f2bf(wv[e]); a1.s[e] = f2bf(wv[8 + e]); }

    f32x4 acc0 = {0.f, 0.f, 0.f, 0.f};
    f32x4 acc1 = {0.f, 0.f, 0.f, 0.f};
    acc0 = __builtin_amdgcn_mfma_f32_16x16x32_bf16(a0.v, zf[0][0], acc0, 0, 0, 0);
    acc0 = __builtin_amdgcn_mfma_f32_16x16x32_bf16(a1.v, zf[0][1], acc0, 0, 0, 0);
    acc1 = __builtin_amdgcn_mfma_f32_16x16x32_bf16(a0.v, zf[1][0], acc1, 0, 0, 0);
    acc1 = __builtin_amdgcn_mfma_f32_16x16x32_bf16(a1.v, zf[1][1], acc1, 0, 0, 0);

    // epilogue: lane holds C rows k = k0 + hi*4 + r, col b = bt*16 + m
    #pragma unroll
    for (int r = 0; r < 4; ++r) {
        const int src  = hi * 4 + r;
        const int row  = __shfl(rowL, src);
        const int ii   = __shfl(iiL, src);
        const float bb = __shfl(bnL, src);
        if (row >= 0) {
            const float x0 = xT[ii * BATCH + m];        // 64B per 16-lane group
            const float x1 = xT[ii * BATCH + 16 + m];
            short* Ep = E + (size_t)row * BATCH;
            Ep[m]      = f2bf((acc0[r] + bb) * x0);     // 32B coalesced per row-half
            Ep[16 + m] = f2bf((acc1[r] + bb) * x1);
        }
    }
}

// ---- segmented reduce: 2 cols/block, 2 waves/col, LDS combine, NO atomics ----
__global__ __launch_bounds__(256) void reduce_bf16(
    const short* __restrict__ E, const int* __restrict__ cnt,
    float* __restrict__ out)
{
    __shared__ float partial[2][BATCH];
    const int wave = threadIdx.x >> 6;          // 0..3
    const int lane = threadIdx.x & 63;
    const int cs   = wave >> 1;                 // column slot in block (0/1)
    const int part = wave & 1;                  // row-half
    const int o    = blockIdx.x * 2 + cs;       // 1024 blocks -> 2048 columns
    const int r  = lane >> 2;                   // 0..15 row-in-group
    const int bg = lane & 3;                    // b-octet
    const int s = o * CAP;
    int c = cnt[o]; if (c > CAP) c = CAP;
    const int e = s + c;

    float acc[8];
    #pragma unroll
    for (int q = 0; q < 8; ++q) acc[q] = 0.f;

    for (int p = s + part * 16 + r; p < e; p += 32) {
        const uint4 v = *reinterpret_cast<const uint4*>(E + (size_t)p * BATCH + bg * 8);
        const unsigned u[4] = {v.x, v.y, v.z, v.w};
        #pragma unroll
        for (int q = 0; q < 4; ++q) {
            acc[2 * q]     += __uint_as_float((u[q] & 0xFFFFu) << 16);
            acc[2 * q + 1] += __uint_as_float(u[q] & 0xFFFF0000u);
        }
    }

    #pragma unroll
    for (int d = 4; d < 64; d <<= 1)
        #pragma unroll
        for (int q = 0; q < 8; ++q)
            acc[q] += __shfl_xor(acc[q], d);

    if (part == 1 && lane < 4) {
        #pragma unroll
        for (int q = 0; q < 8; ++q) partial[cs][bg * 8 + q] = acc[q];
    }
    __syncthreads();
    if (part == 0 && lane < 4) {
        #pragma unroll
        for (int q = 0; q < 8; ++q)
            out[(bg * 8 + q) * OUT_DIM + o] = acc[q] + partial[cs][bg * 8 + q];
    }
}

// ---- last-resort fallback (tiny ws): round-1 atomic scatter ----
__global__ __launch_bounds__(256) void hyper_scatter_kernel(
    const float* __restrict__ x, const float* __restrict__ z,
    const float* __restrict__ W, const float* __restrict__ bn,
    const int* __restrict__ in_idx, const int* __restrict__ out_idx,
    float* __restrict__ out)
{
    __shared__ float zs[BATCH * ZDIM];
    const int tid = threadIdx.x;
    {
        const float4* zg  = reinterpret_cast<const float4*>(z);
        float4*       zsv = reinterpret_cast<float4*>(zs);
        zsv[tid]       = zg[tid];
        zsv[tid + 256] = zg[tid + 256];
    }
    __syncthreads();
    const int k = blockIdx.x * 256 + tid;
    if (k >= NNZ) return;
    float w[ZDIM];
    #pragma unroll
    for (int j = 0; j < ZDIM; ++j) w[j] = W[(size_t)j * NNZ + k];
    const float bk = bn[k];
    const int ii = in_idx[k], oi = out_idx[k];
    const float4* zv = reinterpret_cast<const float4*>(zs);
    #pragma unroll
    for (int b = 0; b < BATCH; ++b) {
        float e = bk;
        #pragma unroll
        for (int j4 = 0; j4 < ZDIM / 4; ++j4) {
            const float4 zz = zv[b * (ZDIM / 4) + j4];
            e = fmaf(zz.x, w[j4 * 4 + 0], e);
            e = fmaf(zz.y, w[j4 * 4 + 1], e);
            e = fmaf(zz.z, w[j4 * 4 + 2], e);
            e = fmaf(zz.w, w[j4 * 4 + 3], e);
        }
        atomicAdd(&out[b * OUT_DIM + oi], e * x[b * IN_DIM + ii]);
    }
}

extern "C" void kernel_launch(void* const* d_in, const int* in_sizes, int n_in,
                              void* d_out, int out_size, void* d_ws, size_t ws_size,
                              hipStream_t stream) {
    const float* x       = (const float*)d_in[0];
    const float* z       = (const float*)d_in[1];
    const float* W       = (const float*)d_in[2];
    const float* bn      = (const float*)d_in[3];
    const int*   in_idx  = (const int*)d_in[4];
    const int*   out_idx = (const int*)d_in[5];
    float*       out     = (float*)d_out;
    char*        ws      = (char*)d_ws;

    if (ws_size >= B_WS_NEEDED) {
        float* xT    = (float*)(ws + OFF_XT);
        short* zbf   = (short*)(ws + OFF_ZBF);
        int*   cnt   = (int*)(ws + OFF_CNT);
        int*   bh    = (int*)(ws + OFF_BH);
        int*   rowOf = (int*)(ws + OFF_ROW);
        short* E     = (short*)(ws + OFF_E);

        prep_x   <<<(BATCH * IN_DIM) / 256, 256, 0, stream>>>(x, z, xT, zbf);
        hist_blk <<<NBLK, 1024, 0, stream>>>(out_idx, bh);
        colscan  <<<OUT_DIM / 4, 256, 0, stream>>>(bh, cnt);
        slot_blk <<<NBLK, 1024, 0, stream>>>(out_idx, bh, rowOf);
        compute_mfma<<<CBLOCKS, 256, 0, stream>>>(zbf, W, bn, in_idx, rowOf, xT, E);
        reduce_bf16 <<<OUT_DIM / 2, 256, 0, stream>>>(E, cnt, out);
    } else {
        hipMemsetAsync(out, 0, (size_t)BATCH * OUT_DIM * sizeof(float), stream);
        const int grid = (NNZ + 255) / 256;
        hyper_scatter_kernel<<<grid, 256, 0, stream>>>(x, z, W, bn, in_idx, out_idx, out);
    }
}

// Round 10
// 42.781 us; speedup vs baseline: 1.7110x; 1.0826x over previous
//
#include <hip/hip_runtime.h>
#include <hip/hip_bf16.h>

#define BATCH   32
#define IN_DIM  2048
#define OUT_DIM 2048
#define ZDIM    64
#define NNZ     209715
#define CAP     160                       // max nnz per col ~138 (mean 102.4); +5.7 sigma
#define TILES   ((NNZ + 15) / 16)         // 13108
#define TPW     2                         // tiles per wave (pipelined; keeps >16 waves/CU)
#define CWAVES  ((TILES + TPW - 1) / TPW) // 6554
#define CBLOCKS ((CWAVES + 3) / 4)        // 1639
#define NBLK    ((NNZ + 1023) / 1024)     // 205 rank blocks

typedef __attribute__((ext_vector_type(8))) short bf16x8;
typedef __attribute__((ext_vector_type(4))) float f32x4;

// ---------------- workspace layout (byte offsets) ----------------
// xT   : float[2048*32]        @ 0           (x transposed)
// zbf  : bf16[32*64]           @ 262144      (z pre-converted to bf16, [b][j])
// cnt  : int[2048]             @ 270336      (per-column counts)
// bh   : int[2048][256]        @ 278528      (TRANSPOSED block hists / bases; 2MB)
// rowOf: int[NNZ]              @ 2375680     (E row for each k)
// E    : bf16[2048*CAP*32]     @ 3214592
#define OFF_XT   0
#define OFF_ZBF  262144
#define OFF_CNT  270336
#define OFF_BH   278528
#define OFF_ROW  2375680
#define OFF_E    3214592
#define B_WS_NEEDED (OFF_E + (size_t)OUT_DIM * CAP * BATCH * 2)   // ~24.2 MB

__device__ __forceinline__ short f2bf(float f) {      // RNE f32 -> bf16
    unsigned u = __float_as_uint(f);
    u += 0x7fffu + ((u >> 16) & 1u);
    return (short)(u >> 16);
}

// ---- stage 1 (fused): per-block histogram + x transpose + z bf16 convert ----
__global__ __launch_bounds__(1024) void hist_prep(
    const int* __restrict__ out_idx, const float* __restrict__ x,
    const float* __restrict__ z, int* __restrict__ bh,
    float* __restrict__ xT, short* __restrict__ zbf)
{
    __shared__ int lh[OUT_DIM];
    const int t = threadIdx.x, blk = blockIdx.x;
    lh[t] = 0; lh[t + 1024] = 0;
    __syncthreads();
    const int gid = blk * 1024 + t;
    if (gid < BATCH * IN_DIM) {                       // blocks 0..63 also do prep
        const int b = gid >> 11, i = gid & 2047;
        xT[i * BATCH + b] = x[gid];
        if (gid < BATCH * ZDIM) zbf[gid] = f2bf(z[gid]);
    }
    if (gid < NNZ) atomicAdd(&lh[out_idx[gid]], 1);   // LDS atomic: ~free
    __syncthreads();
    bh[t * 256 + blk]          = lh[t];               // transposed; L2-resident
    bh[(t + 1024) * 256 + blk] = lh[t + 1024];
}

// ---- stage 2: wave-per-column shuffle scan over blocks; emit cnt ----
__global__ __launch_bounds__(256) void colscan(
    int* __restrict__ bh, int* __restrict__ cnt)
{
    const int o    = blockIdx.x * 4 + (threadIdx.x >> 6);  // 2048 columns
    const int lane = threadIdx.x & 63;
    const int i0   = lane * 4;
    int4 v = *reinterpret_cast<int4*>(bh + o * 256 + i0);  // coalesced 1KB/wave
    const int a = (i0 + 0 < NBLK) ? v.x : 0;               // mask poison tail
    const int b = (i0 + 1 < NBLK) ? v.y : 0;
    const int c = (i0 + 2 < NBLK) ? v.z : 0;
    const int d = (i0 + 3 < NBLK) ? v.w : 0;
    const int s1 = a + b, s2 = s1 + c, tot = s2 + d;
    int inc = tot;
    #pragma unroll
    for (int t = 1; t < 64; t <<= 1) {
        const int n = __shfl_up(inc, t);
        if (lane >= t) inc += n;
    }
    const int exc = inc - tot;
    int4 w; w.x = exc; w.y = exc + a; w.z = exc + s1; w.w = exc + s2;
    *reinterpret_cast<int4*>(bh + o * 256 + i0) = w;
    if (lane == 63) cnt[o] = inc;
}

// ---- stage 3: local LDS rank + block base -> rowOf[k] ----
__global__ __launch_bounds__(1024) void slot_blk(
    const int* __restrict__ out_idx, const int* __restrict__ bh,
    int* __restrict__ rowOf)
{
    __shared__ int lh[OUT_DIM];
    const int t = threadIdx.x, blk = blockIdx.x;
    lh[t] = 0; lh[t + 1024] = 0;
    __syncthreads();
    const int k = blk * 1024 + t;
    if (k < NNZ) {
        const int oi  = out_idx[k];
        const int r   = atomicAdd(&lh[oi], 1);            // rank within block
        const int pos = bh[oi * 256 + blk] + r;           // + blocks before
        rowOf[k] = (pos < CAP) ? oi * CAP + pos : -1;
    }
}

// ---- stage 4: MFMA compute, 2 tiles/wave, explicit issue-order pipeline ----
// Issue order: zbf -> metadata -> W(t0) -> W(t1) -> shfl+xT prefetch ->
// cvt0/MFMA0/epi0 -> cvt1/MFMA1/epi1. In-order vmcnt retirement means each
// consumer waits only for its producers; tile-1 loads ride under tile-0 math.
__global__ __launch_bounds__(256, 4) void compute_mfma(
    const short* __restrict__ zbf, const float* __restrict__ W,
    const float* __restrict__ bn, const int* __restrict__ in_idx,
    const int* __restrict__ rowOf, const float* __restrict__ xT,
    short* __restrict__ E)
{
    const int lane = threadIdx.x & 63;
    const int m    = lane & 15;            // A-row (k in tile) / B,C col (b)
    const int hi   = lane >> 4;            // k-slice group for inputs
    const int wid  = blockIdx.x * 4 + (threadIdx.x >> 6);
    const int t0   = wid * TPW;
    if (t0 >= TILES) return;

    // z fragments first (tiny, L1-resident; retire almost immediately)
    bf16x8 zf[2][2];
    #pragma unroll
    for (int bt = 0; bt < 2; ++bt)
        #pragma unroll
        for (int jt = 0; jt < 2; ++jt)
            zf[bt][jt] = *reinterpret_cast<const bf16x8*>(
                zbf + (bt * 16 + m) * ZDIM + jt * 32 + hi * 8);

    // per-k metadata for both tiles (lanes 0..15; coalesced 64B)
    int rowL[2] = {-1, -1}, iiL[2] = {0, 0};
    float bnL[2] = {0.f, 0.f};
    #pragma unroll
    for (int tt = 0; tt < TPW; ++tt) {
        const int t = t0 + tt;
        if (t < TILES && lane < 16) {
            const int kk = t * 16 + lane;
            if (kk < NNZ) { rowL[tt] = rowOf[kk]; iiL[tt] = in_idx[kk]; bnL[tt] = bn[kk]; }
        }
    }

    // W for both tiles: 32 coalesced dword loads, all in flight together
    float wv[2][16];
    #pragma unroll
    for (int tt = 0; tt < TPW; ++tt) {
        const int t  = (t0 + tt < TILES) ? (t0 + tt) : (TILES - 1);
        const int kA = (t * 16 + m < NNZ) ? (t * 16 + m) : (NNZ - 1);
        const float* wp = W + (size_t)(hi * 8) * NNZ + kA;
        #pragma unroll
        for (int e = 0; e < 8; ++e) wv[tt][e]     = wp[(size_t)e * NNZ];
        #pragma unroll
        for (int e = 0; e < 8; ++e) wv[tt][8 + e] = wp[(size_t)(32 + e) * NNZ];
    }

    // broadcast row/ii, prefetch xT gathers NOW (hide under W drain)
    int   row_[2][4];
    float x0_[2][4], x1_[2][4];
    #pragma unroll
    for (int tt = 0; tt < TPW; ++tt)
        #pragma unroll
        for (int r = 0; r < 4; ++r) {
            const int src = hi * 4 + r;
            row_[tt][r] = __shfl(rowL[tt], src);
            const int ii = __shfl(iiL[tt], src);
            x0_[tt][r] = xT[ii * BATCH + m];        // 64B per 16-lane group
            x1_[tt][r] = xT[ii * BATCH + 16 + m];
        }

    // per-tile: cvt -> 4 MFMA -> epilogue
    #pragma unroll
    for (int tt = 0; tt < TPW; ++tt) {
        union { bf16x8 v; short s[8]; } a0, a1;
        #pragma unroll
        for (int e = 0; e < 8; ++e) { a0.s[e] = f2bf(wv[tt][e]); a1.s[e] = f2bf(wv[tt][8 + e]); }

        f32x4 acc0 = {0.f, 0.f, 0.f, 0.f};
        f32x4 acc1 = {0.f, 0.f, 0.f, 0.f};
        acc0 = __builtin_amdgcn_mfma_f32_16x16x32_bf16(a0.v, zf[0][0], acc0, 0, 0, 0);
        acc0 = __builtin_amdgcn_mfma_f32_16x16x32_bf16(a1.v, zf[0][1], acc0, 0, 0, 0);
        acc1 = __builtin_amdgcn_mfma_f32_16x16x32_bf16(a0.v, zf[1][0], acc1, 0, 0, 0);
        acc1 = __builtin_amdgcn_mfma_f32_16x16x32_bf16(a1.v, zf[1][1], acc1, 0, 0, 0);

        #pragma unroll
        for (int r = 0; r < 4; ++r) {
            const int row = row_[tt][r];
            if (row >= 0) {
                const float bb = __shfl(bnL[tt], hi * 4 + r);   // LDS-pipe, cheap
                short* Ep = E + (size_t)row * BATCH;
                Ep[m]      = f2bf((acc0[r] + bb) * x0_[tt][r]); // 32B/row-half
                Ep[16 + m] = f2bf((acc1[r] + bb) * x1_[tt][r]);
            }
        }
    }
}

// ---- stage 5: segmented reduce, 1 wave/col, 4 cols/block, no LDS/atomics ----
__global__ __launch_bounds__(256) void reduce_bf16(
    const short* __restrict__ E, const int* __restrict__ cnt,
    float* __restrict__ out)
{
    const int o    = blockIdx.x * 4 + (threadIdx.x >> 6);   // 512 blocks
    const int lane = threadIdx.x & 63;
    const int r  = lane >> 2;                   // 0..15 row-in-group
    const int bg = lane & 3;                    // b-octet
    const int s = o * CAP;
    int c = cnt[o]; if (c > CAP) c = CAP;
    const int e = s + c;

    float acc[8];
    #pragma unroll
    for (int q = 0; q < 8; ++q) acc[q] = 0.f;

    for (int p = s + r; p < e; p += 16) {       // wave reads 1KB contiguous/iter
        const uint4 v = *reinterpret_cast<const uint4*>(E + (size_t)p * BATCH + bg * 8);
        const unsigned u[4] = {v.x, v.y, v.z, v.w};
        #pragma unroll
        for (int q = 0; q < 4; ++q) {
            acc[2 * q]     += __uint_as_float((u[q] & 0xFFFFu) << 16);
            acc[2 * q + 1] += __uint_as_float(u[q] & 0xFFFF0000u);
        }
    }

    #pragma unroll
    for (int d = 4; d < 64; d <<= 1)
        #pragma unroll
        for (int q = 0; q < 8; ++q)
            acc[q] += __shfl_xor(acc[q], d);

    if (lane < 4) {
        #pragma unroll
        for (int q = 0; q < 8; ++q)
            out[(bg * 8 + q) * OUT_DIM + o] = acc[q];
    }
}

// ---- last-resort fallback (tiny ws): round-1 atomic scatter ----
__global__ __launch_bounds__(256) void hyper_scatter_kernel(
    const float* __restrict__ x, const float* __restrict__ z,
    const float* __restrict__ W, const float* __restrict__ bn,
    const int* __restrict__ in_idx, const int* __restrict__ out_idx,
    float* __restrict__ out)
{
    __shared__ float zs[BATCH * ZDIM];
    const int tid = threadIdx.x;
    {
        const float4* zg  = reinterpret_cast<const float4*>(z);
        float4*       zsv = reinterpret_cast<float4*>(zs);
        zsv[tid]       = zg[tid];
        zsv[tid + 256] = zg[tid + 256];
    }
    __syncthreads();
    const int k = blockIdx.x * 256 + tid;
    if (k >= NNZ) return;
    float w[ZDIM];
    #pragma unroll
    for (int j = 0; j < ZDIM; ++j) w[j] = W[(size_t)j * NNZ + k];
    const float bk = bn[k];
    const int ii = in_idx[k], oi = out_idx[k];
    const float4* zv = reinterpret_cast<const float4*>(zs);
    #pragma unroll
    for (int b = 0; b < BATCH; ++b) {
        float e = bk;
        #pragma unroll
        for (int j4 = 0; j4 < ZDIM / 4; ++j4) {
            const float4 zz = zv[b * (ZDIM / 4) + j4];
            e = fmaf(zz.x, w[j4 * 4 + 0], e);
            e = fmaf(zz.y, w[j4 * 4 + 1], e);
            e = fmaf(zz.z, w[j4 * 4 + 2], e);
            e = fmaf(zz.w, w[j4 * 4 + 3], e);
        }
        atomicAdd(&out[b * OUT_DIM + oi], e * x[b * IN_DIM + ii]);
    }
}

extern "C" void kernel_launch(void* const* d_in, const int* in_sizes, int n_in,
                              void* d_out, int out_size, void* d_ws, size_t ws_size,
                              hipStream_t stream) {
    const float* x       = (const float*)d_in[0];
    const float* z       = (const float*)d_in[1];
    const float* W       = (const float*)d_in[2];
    const float* bn      = (const float*)d_in[3];
    const int*   in_idx  = (const int*)d_in[4];
    const int*   out_idx = (const int*)d_in[5];
    float*       out     = (float*)d_out;
    char*        ws      = (char*)d_ws;

    if (ws_size >= B_WS_NEEDED) {
        float* xT    = (float*)(ws + OFF_XT);
        short* zbf   = (short*)(ws + OFF_ZBF);
        int*   cnt   = (int*)(ws + OFF_CNT);
        int*   bh    = (int*)(ws + OFF_BH);
        int*   rowOf = (int*)(ws + OFF_ROW);
        short* E     = (short*)(ws + OFF_E);

        hist_prep<<<NBLK, 1024, 0, stream>>>(out_idx, x, z, bh, xT, zbf);
        colscan  <<<OUT_DIM / 4, 256, 0, stream>>>(bh, cnt);
        slot_blk <<<NBLK, 1024, 0, stream>>>(out_idx, bh, rowOf);
        compute_mfma<<<CBLOCKS, 256, 0, stream>>>(zbf, W, bn, in_idx, rowOf, xT, E);
        reduce_bf16 <<<OUT_DIM / 4, 256, 0, stream>>>(E, cnt, out);
    } else {
        hipMemsetAsync(out, 0, (size_t)BATCH * OUT_DIM * sizeof(float), stream);
        const int grid = (NNZ + 255) / 256;
        hyper_scatter_kernel<<<grid, 256, 0, stream>>>(x, z, W, bn, in_idx, out_idx, out);
    }
}